// Round 1
// baseline (1052.860 us; speedup 1.0000x reference)
//
#include <hip/hip_runtime.h>
#include <math.h>

#define NSAMP 131072
#define HID 64

__device__ __forceinline__ float fast_tanh(float x) {
    // tanh(x) = sign(x) * (1 - 2/(exp(2|x|)+1)); exp via v_exp_f32 (2^t)
    float ax = fabsf(x);
    float e = __builtin_amdgcn_exp2f(ax * 2.88539008177793f); // 2*log2(e)
    float r = 1.0f - 2.0f * __builtin_amdgcn_rcpf(e + 1.0f);
    return copysignf(r, x);
}

__global__ __launch_bounds__(256, 2)
void cnf_logp_kernel(const float* __restrict__ xin, const float* __restrict__ tin,
                     const float* __restrict__ W1, const float* __restrict__ b1,
                     const float* __restrict__ W2, const float* __restrict__ b2,
                     const float* __restrict__ W3, const float* __restrict__ b3,
                     const float* __restrict__ vol, float* __restrict__ out)
{
    // LDS: weights are wave-uniform -> all reads are broadcast (conflict-free)
    __shared__ float4 sW1t[HID];      // (W1[0][k], W1[1][k], W1[2][k], W1[3][k])
    __shared__ float  sb1[HID];
    __shared__ float4 sW2v[HID * 16]; // [k][j4] row-major, j fastest
    __shared__ float4 sHv [HID * 16]; // H[k][j] = W2[k][j] * sum_i W1[i][k]*W3[j][i]
    __shared__ float4 sb2v[16];
    __shared__ float4 sW3v[HID];      // (W3[j][0..2], 0)
    __shared__ float  sb3[4];

    const int tid = threadIdx.x;

    for (int i = tid; i < HID; i += 256) {
        sW1t[i] = make_float4(W1[0*64 + i], W1[1*64 + i], W1[2*64 + i], W1[3*64 + i]);
        sb1[i]  = b1[i];
        sW3v[i] = make_float4(W3[i*3 + 0], W3[i*3 + 1], W3[i*3 + 2], 0.0f);
    }
    float* sW2f = (float*)sW2v;
    float* sHf  = (float*)sHv;
    for (int i = tid; i < HID * HID; i += 256) {
        int k = i >> 6, j = i & 63;
        float w2 = W2[i];          // W2[k][j], row-major
        sW2f[i] = w2;
        float g = W1[0*64 + k] * W3[j*3 + 0]
                + W1[1*64 + k] * W3[j*3 + 1]
                + W1[2*64 + k] * W3[j*3 + 2];
        sHf[i] = w2 * g;
    }
    if (tid < 16) sb2v[tid] = make_float4(b2[tid*4+0], b2[tid*4+1], b2[tid*4+2], b2[tid*4+3]);
    if (tid < 4)  sb3[tid]  = (tid < 3) ? b3[tid] : 0.0f;
    __syncthreads();

    const int idx = blockIdx.x * 256 + tid;
    if (idx >= NSAMP) return;

    const float x0v = xin[idx*3 + 0], x1v = xin[idx*3 + 1], x2v = xin[idx*3 + 2];
    const float t0  = tin[idx];

    float z0 = x0v, z1 = x1v, z2 = x2v;   // RK4 base point
    float dacc = 0.0f;                     // integrated t0*div
    const float hstep = 0.25f;
    float kz0 = 0.f, kz1 = 0.f, kz2 = 0.f; // previous stage velocity
    float sa0 = 0.f, sa1 = 0.f, sa2 = 0.f; // per-step weighted z accumulator

    #pragma unroll 1
    for (int it = 0; it < 16; ++it) {
        const int st   = it & 3;
        const int step = it >> 2;
        const float alpha = (st == 0) ? 0.0f : ((st == 3) ? hstep : 0.5f * hstep);
        const float wgt   = (st == 1 || st == 2) ? (hstep * (1.0f/3.0f)) : (hstep * (1.0f/6.0f));
        const float s     = (float)step * hstep + alpha; // soff == alpha for RK4
        const float zi0 = fmaf(alpha, kz0, z0);
        const float zi1 = fmaf(alpha, kz1, z1);
        const float zi2 = fmaf(alpha, kz2, z2);
        const float tt  = t0 * (1.0f - s);

        // ---- layer 1: h1 = tanh([z,tt] @ W1 + b1), s1 = 1 - h1^2 ----
        float h1[HID], s1[HID];
        #pragma unroll
        for (int k = 0; k < HID; ++k) {
            float4 w1 = sW1t[k];
            float pre = fmaf(zi0, w1.x, fmaf(zi1, w1.y, fmaf(zi2, w1.z, fmaf(tt, w1.w, sb1[k]))));
            float h = fast_tanh(pre);
            h1[k] = h;
            s1[k] = 1.0f - h * h;
        }

        // ---- layer 2 + bilinear divergence + layer 3, blocked by 4 j's ----
        float f0 = sb3[0], f1 = sb3[1], f2 = sb3[2], dv = 0.0f;
        #pragma unroll 1
        for (int j4 = 0; j4 < 16; ++j4) {
            float4 bb = sb2v[j4];
            float a0 = bb.x, a1 = bb.y, a2 = bb.z, a3 = bb.w;
            float d0 = 0.f, d1 = 0.f, d2 = 0.f, d3 = 0.f;
            #pragma unroll
            for (int k = 0; k < HID; ++k) {
                float4 w2 = sW2v[k*16 + j4];
                float4 hh = sHv [k*16 + j4];
                float hk = h1[k], sk = s1[k];
                a0 = fmaf(hk, w2.x, a0); a1 = fmaf(hk, w2.y, a1);
                a2 = fmaf(hk, w2.z, a2); a3 = fmaf(hk, w2.w, a3);
                d0 = fmaf(sk, hh.x, d0); d1 = fmaf(sk, hh.y, d1);
                d2 = fmaf(sk, hh.z, d2); d3 = fmaf(sk, hh.w, d3);
            }
            float hv, sv; float4 w3;
            hv = fast_tanh(a0); sv = 1.0f - hv*hv; w3 = sW3v[j4*4 + 0];
            f0 = fmaf(hv, w3.x, f0); f1 = fmaf(hv, w3.y, f1); f2 = fmaf(hv, w3.z, f2);
            dv = fmaf(sv, d0, dv);
            hv = fast_tanh(a1); sv = 1.0f - hv*hv; w3 = sW3v[j4*4 + 1];
            f0 = fmaf(hv, w3.x, f0); f1 = fmaf(hv, w3.y, f1); f2 = fmaf(hv, w3.z, f2);
            dv = fmaf(sv, d1, dv);
            hv = fast_tanh(a2); sv = 1.0f - hv*hv; w3 = sW3v[j4*4 + 2];
            f0 = fmaf(hv, w3.x, f0); f1 = fmaf(hv, w3.y, f1); f2 = fmaf(hv, w3.z, f2);
            dv = fmaf(sv, d2, dv);
            hv = fast_tanh(a3); sv = 1.0f - hv*hv; w3 = sW3v[j4*4 + 3];
            f0 = fmaf(hv, w3.x, f0); f1 = fmaf(hv, w3.y, f1); f2 = fmaf(hv, w3.z, f2);
            dv = fmaf(sv, d3, dv);
        }

        // ---- dyn outputs: dz/ds = -t0*f ; ddiv/ds = t0*div ----
        const float v0 = -t0 * f0, v1 = -t0 * f1, v2 = -t0 * f2;
        const float vd =  t0 * dv;
        kz0 = v0; kz1 = v1; kz2 = v2;
        dacc = fmaf(wgt, vd, dacc);
        if (st == 0) { sa0 = wgt * v0; sa1 = wgt * v1; sa2 = wgt * v2; }
        else         { sa0 = fmaf(wgt, v0, sa0); sa1 = fmaf(wgt, v1, sa1); sa2 = fmaf(wgt, v2, sa2); }
        if (st == 3) { z0 += sa0; z1 += sa1; z2 += sa2; }
    }

    // ---- mask (t>0), grid_sample trilinear zeros-padding, logp ----
    const bool m = (t0 > 0.0f);
    const float q0 = m ? z0 : x0v;
    const float q1 = m ? z1 : x1v;
    const float q2 = m ? z2 : x2v;
    const float dfin = m ? dacc : 0.0f;

    // coords = q/5 in (x,y,z); px indexes W, py H, pz D; D=H=W=100
    const float px = ((q0 * 0.2f + 1.0f) * 100.0f - 1.0f) * 0.5f;
    const float py = ((q1 * 0.2f + 1.0f) * 100.0f - 1.0f) * 0.5f;
    const float pz = ((q2 * 0.2f + 1.0f) * 100.0f - 1.0f) * 0.5f;
    const float fx = floorf(px), fy = floorf(py), fz = floorf(pz);
    const int ix0 = (int)fx, iy0 = (int)fy, iz0 = (int)fz;
    const float wx1 = px - fx, wy1 = py - fy, wz1 = pz - fz;

    float gs = 0.0f;
    #pragma unroll
    for (int c = 0; c < 8; ++c) {
        const int dxc = c & 1, dyc = (c >> 1) & 1, dzc = (c >> 2) & 1;
        const int ix = ix0 + dxc, iy = iy0 + dyc, iz = iz0 + dzc;
        const float w = (dxc ? wx1 : 1.0f - wx1)
                      * (dyc ? wy1 : 1.0f - wy1)
                      * (dzc ? wz1 : 1.0f - wz1);
        if (ix >= 0 && ix < 100 && iy >= 0 && iy < 100 && iz >= 0 && iz < 100)
            gs += vol[(iz * 100 + iy) * 100 + ix] * w;
    }

    out[idx] = gs - dfin;
}

extern "C" void kernel_launch(void* const* d_in, const int* in_sizes, int n_in,
                              void* d_out, int out_size, void* d_ws, size_t ws_size,
                              hipStream_t stream) {
    const float* x    = (const float*)d_in[0];
    const float* t    = (const float*)d_in[1];
    const float* W1   = (const float*)d_in[2];
    const float* b1   = (const float*)d_in[3];
    const float* W2   = (const float*)d_in[4];
    const float* b2   = (const float*)d_in[5];
    const float* W3   = (const float*)d_in[6];
    const float* b3   = (const float*)d_in[7];
    const float* vol  = (const float*)d_in[8];
    float* out = (float*)d_out;

    dim3 grid(NSAMP / 256), block(256);
    cnf_logp_kernel<<<grid, block, 0, stream>>>(x, t, W1, b1, W2, b2, W3, b3, vol, out);
}